// Round 1
// baseline (7357.213 us; speedup 1.0000x reference)
//
#include <hip/hip_runtime.h>
#include <cstddef>

// Problem constants
#define BATCH 64
#define SEQL  512
#define IDIM  256
#define HDIM  256
#define G7    1792            // 7*H
#define OSTRIDE (64*513*256)  // per-output-tensor elements = 8,404,992
#define XG_ELEMS ((size_t)BATCH*SEQL*G7)       // 58,720,256
#define XG_BYTES (XG_ELEMS*4)                  // 234,881,024

// ---------------------------------------------------------------------------
// Kernel 0: pack Wh (7H x H row-major) into float4 tiles for the recurrence.
// Wp[k2][j] = { Wh[j][2k2], Wh[j+896][2k2], Wh[j][2k2+1], Wh[j+896][2k2+1] }
// so thread j's load at step-k2 is 16B and coalesced across j.
// ---------------------------------------------------------------------------
__global__ __launch_bounds__(256) void pack_wh(const float* __restrict__ Wh,
                                               float4* __restrict__ Wp) {
    int idx = blockIdx.x * 256 + threadIdx.x;     // 0 .. 114687
    if (idx >= 128 * 896) return;
    int k2 = idx / 896;
    int j  = idx % 896;
    float4 v;
    v.x = Wh[(size_t)j * 256 + 2 * k2];
    v.y = Wh[(size_t)(j + 896) * 256 + 2 * k2];
    v.z = Wh[(size_t)j * 256 + 2 * k2 + 1];
    v.w = Wh[(size_t)(j + 896) * 256 + 2 * k2 + 1];
    Wp[(size_t)k2 * 896 + j] = v;
}

// ---------------------------------------------------------------------------
// Kernel 1: zero-fill d_out (harness poisons it to 0xAA before every launch;
// masked steps and the t=0 row must be exactly 0).
// ---------------------------------------------------------------------------
__global__ void zero_out(float4* __restrict__ p, int n4) {
    int i = blockIdx.x * blockDim.x + threadIdx.x;
    int stride = gridDim.x * blockDim.x;
    for (; i < n4; i += stride) p[i] = make_float4(0.f, 0.f, 0.f, 0.f);
}

// ---------------------------------------------------------------------------
// Kernel 2: xg = x @ Wx^T + bx   (M=32768, N=1792, K=256), fp32 LDS-tiled.
// Skips M-tiles whose whole 128-row t-range is masked out.
// ---------------------------------------------------------------------------
__global__ __launch_bounds__(256) void gemm_xg(const float* __restrict__ X,
                                               const float* __restrict__ W,
                                               const float* __restrict__ bx,
                                               const int* __restrict__ seq_lens,
                                               float* __restrict__ xg) {
    __shared__ float As[8][132];
    __shared__ float Bs[8][132];
    const int m0 = blockIdx.y * 128;
    const int n0 = blockIdx.x * 128;
    const int b  = m0 >> 9;             // 512 rows per batch, 128 | 512
    if ((m0 & 511) >= seq_lens[b]) return;   // fully-masked tile: dead

    const int tid = threadIdx.x;
    const int lr  = tid >> 1;           // 0..127 row in tile
    const int lc  = (tid & 1) << 2;     // k sub-offset 0 or 4
    const int tx  = tid & 15;
    const int ty  = tid >> 4;

    const float* Aptr = X + (size_t)(m0 + lr) * 256 + lc;
    const float* Bptr = W + (size_t)(n0 + lr) * 256 + lc;

    float acc[8][8] = {};

    for (int k0 = 0; k0 < 256; k0 += 8) {
        float4 av = *(const float4*)(Aptr + k0);
        float4 bv = *(const float4*)(Bptr + k0);
        __syncthreads();
        As[lc + 0][lr] = av.x; As[lc + 1][lr] = av.y;
        As[lc + 2][lr] = av.z; As[lc + 3][lr] = av.w;
        Bs[lc + 0][lr] = bv.x; Bs[lc + 1][lr] = bv.y;
        Bs[lc + 2][lr] = bv.z; Bs[lc + 3][lr] = bv.w;
        __syncthreads();
#pragma unroll
        for (int kk = 0; kk < 8; ++kk) {
            float a[8], bb[8];
#pragma unroll
            for (int i = 0; i < 8; ++i) a[i] = As[kk][ty * 8 + i];
#pragma unroll
            for (int j = 0; j < 8; ++j) bb[j] = Bs[kk][tx * 8 + j];
#pragma unroll
            for (int i = 0; i < 8; ++i)
#pragma unroll
                for (int j = 0; j < 8; ++j) acc[i][j] += a[i] * bb[j];
        }
    }

    float bxa[8];
#pragma unroll
    for (int j = 0; j < 8; ++j) bxa[j] = bx[n0 + tx * 8 + j];
#pragma unroll
    for (int i = 0; i < 8; ++i) {
        float* orow = xg + (size_t)(m0 + ty * 8 + i) * G7 + n0 + tx * 8;
        float4 v0 = make_float4(acc[i][0] + bxa[0], acc[i][1] + bxa[1],
                                acc[i][2] + bxa[2], acc[i][3] + bxa[3]);
        float4 v1 = make_float4(acc[i][4] + bxa[4], acc[i][5] + bxa[5],
                                acc[i][6] + bxa[6], acc[i][7] + bxa[7]);
        *(float4*)(orow)     = v0;
        *(float4*)(orow + 4) = v1;
    }
}

// ---------------------------------------------------------------------------
// Kernel 3: the sequential CT-LSTM recurrence. One block per batch element.
// 896 threads: thread j owns gate rows j and j+896. h/c/g live in LDS.
// Wh is streamed (packed float4, coalesced) from L2 every step.
// ---------------------------------------------------------------------------
__device__ __forceinline__ float act_gate(float v, int gate) {
    if (gate == 2) return tanhf(v);                       // z
    if (gate == 4) {                                      // d: softplus (stable)
        return fmaxf(v, 0.f) + log1pf(expf(-fabsf(v)));
    }
    return 1.f / (1.f + expf(-v));                        // sigmoids
}

__global__ __launch_bounds__(896) void ctlstm_rec(const float* __restrict__ xg,
                                                  const float* __restrict__ dt,
                                                  const int* __restrict__ seq_lens,
                                                  const float4* __restrict__ Wp,
                                                  const float* __restrict__ bh,
                                                  float* __restrict__ out) {
    __shared__ float h_lds[256];
    __shared__ float c_lds[256];
    __shared__ float g_lds[1792];

    const int b  = blockIdx.x;
    const int sl = seq_lens[b];
    const int j  = threadIdx.x;

    if (j < 256) { h_lds[j] = 0.f; c_lds[j] = 0.f; }
    const float bh0 = bh[j];
    const float bh1 = bh[j + 896];
    const int g0 = j >> 8;            // 0..3  (i,f,z,o-low)
    const int g1 = (j + 896) >> 8;    // 3..6  (o-high,d,ib,fb)
    __syncthreads();

    for (int t = 0; t < sl; ++t) {
        const float* xr = xg + ((size_t)b * SEQL + t) * G7;
        float acc0 = xr[j] + bh0;
        float acc1 = xr[j + 896] + bh1;

        const float4* wp = Wp + j;
#pragma unroll 8
        for (int k2 = 0; k2 < 128; ++k2) {
            float4 w  = wp[(size_t)k2 * 896];
            float2 h2 = *(const float2*)&h_lds[2 * k2];
            acc0 += w.x * h2.x; acc1 += w.y * h2.x;
            acc0 += w.z * h2.y; acc1 += w.w * h2.y;
        }

        g_lds[j]       = act_gate(acc0, g0);
        g_lds[j + 896] = act_gate(acc1, g1);
        __syncthreads();

        if (j < 256) {
            float iv  = g_lds[j];
            float fv  = g_lds[256 + j];
            float zv  = g_lds[512 + j];
            float ov  = g_lds[768 + j];
            float dv  = g_lds[1024 + j];
            float ibv = g_lds[1280 + j];
            float fbv = g_lds[1536 + j];
            float cn  = c_lds[j];

            float c   = fv * cn + iv * zv;
            float hh  = ov * tanhf(c);
            float cb  = fbv * cn + ibv * zv;
            float dtv = dt[b * SEQL + t];
            float ct  = cb + (c - cb) * expf(-dv * dtv);
            float ht  = ov * tanhf(ct);

            h_lds[j] = ht;
            c_lds[j] = ct;

            size_t base = ((size_t)b * 513 + t + 1) * 256 + j;
            out[base]                = ht;   // ys[0] = hn2
            out[OSTRIDE + base]      = hh;   // masked h
            out[2 * (size_t)OSTRIDE + base] = c;    // masked c
            out[3 * (size_t)OSTRIDE + base] = cb;   // masked c_bar
            out[4 * (size_t)OSTRIDE + base] = ov;   // masked o
            out[5 * (size_t)OSTRIDE + base] = dv;   // masked d
        }
        __syncthreads();
    }
}

// ---------------------------------------------------------------------------
extern "C" void kernel_launch(void* const* d_in, const int* in_sizes, int n_in,
                              void* d_out, int out_size, void* d_ws, size_t ws_size,
                              hipStream_t stream) {
    const float* x   = (const float*)d_in[0];
    const float* dt  = (const float*)d_in[1];
    const int*   sl  = (const int*)d_in[2];
    const float* Wx  = (const float*)d_in[3];
    const float* bx  = (const float*)d_in[4];
    const float* Wh  = (const float*)d_in[5];
    const float* bh  = (const float*)d_in[6];
    float* out = (float*)d_out;

    float*  xg = (float*)d_ws;
    float4* Wp = (float4*)((char*)d_ws + XG_BYTES);

    // 0: pack Wh for coalesced recurrence loads
    pack_wh<<<448, 256, 0, stream>>>(Wh, Wp);

    // 1: zero-fill output (poisoned 0xAA each launch)
    int n4 = out_size / 4;   // out_size = 50,466,816 (divisible by 4)
    zero_out<<<2048, 256, 0, stream>>>((float4*)out, n4);

    // 2: input GEMM xg = x @ Wx^T + bx   (masked tiles skipped)
    dim3 ggrid(G7 / 128, (BATCH * SEQL) / 128);   // 14 x 256
    gemm_xg<<<ggrid, 256, 0, stream>>>(x, Wx, bx, sl, xg);

    // 3: sequential recurrence, one block per batch element
    ctlstm_rec<<<BATCH, 896, 0, stream>>>(xg, dt, sl, Wp, bh, out);
}